// Round 5
// baseline (193.381 us; speedup 1.0000x reference)
//
#include <hip/hip_runtime.h>
#include <hip/hip_bf16.h>
#include <stdint.h>

typedef __bf16 bf16;
typedef __bf16 bf16x8 __attribute__((ext_vector_type(8)));
typedef __bf16 bf16x4 __attribute__((ext_vector_type(4)));
typedef float  f32x4  __attribute__((ext_vector_type(4)));
typedef float  f32x16 __attribute__((ext_vector_type(16)));

#define H_   16
#define D_   1024
#define B_   4
#define S_   2048
#define M_   (B_*S_)      // 8192 rows
#define REGION 8388608LL  // elems per Q/K/V region

// Q is pre-scaled by 1/sqrt(dk) * log2(e) so attention uses raw exp2.
#define QSCALE 0.18033688011112042f

// ---------------- prep kernels ----------------

__global__ void cast_x_kernel(const float* __restrict__ x, bf16* __restrict__ xb) {
    const int i = blockIdx.x * 256 + threadIdx.x;
    const float4* src = reinterpret_cast<const float4*>(x) + (size_t)i * 2;
    float4 a = src[0], b = src[1];
    bf16x8 o;
    o[0]=(bf16)a.x; o[1]=(bf16)a.y; o[2]=(bf16)a.z; o[3]=(bf16)a.w;
    o[4]=(bf16)b.x; o[5]=(bf16)b.y; o[6]=(bf16)b.z; o[7]=(bf16)b.w;
    *reinterpret_cast<bf16x8*>(xb + (size_t)i * 8) = o;
}

__global__ void prep_wqkv_kernel(const float* __restrict__ Wq, const float* __restrict__ Wk,
                                 const float* __restrict__ Wv, const float* __restrict__ bq,
                                 const float* __restrict__ bk, const float* __restrict__ bv,
                                 bf16* __restrict__ WqkvT, float* __restrict__ qkvb) {
    const int t = blockIdx.x * 256 + threadIdx.x;
    const int n = t >> 7, d0 = (t & 127) << 3;
    const int which = n >> 10, hh = (n >> 6) & 15, dk = n & 63;
    const float* W = (which == 0) ? Wq : (which == 1) ? Wk : Wv;
    const float* src = W + (size_t)hh * 65536 + (size_t)d0 * 64 + dk;
    bf16x8 o;
#pragma unroll
    for (int i = 0; i < 8; ++i) o[i] = (bf16)src[(size_t)i * 64];
    *reinterpret_cast<bf16x8*>(WqkvT + (size_t)n * D_ + d0) = o;
    if (d0 == 0) {
        const float* bb = (which == 0) ? bq : (which == 1) ? bk : bv;
        qkvb[n] = bb[n & 1023];
    }
}

__global__ void prep_wo_kernel(const float* __restrict__ Wo, bf16* __restrict__ WoT) {
    __shared__ float tile[64][65];
    const int k0 = blockIdx.x * 64, n0 = blockIdx.y * 64;
    const int t = threadIdx.x;
#pragma unroll
    for (int i = 0; i < 16; ++i) {
        int idx = t + i * 256, r = idx >> 6, c = idx & 63;
        tile[r][c] = Wo[(size_t)(k0 + r) * D_ + n0 + c];
    }
    __syncthreads();
#pragma unroll
    for (int i = 0; i < 16; ++i) {
        int idx = t + i * 256, n = idx >> 6, k = idx & 63;
        WoT[(size_t)(n0 + n) * D_ + k0 + k] = (bf16)tile[k][n];
    }
}

// ---------------- GEMM: C[M][N] = A[M][1024] * Bt[N][1024]^T + bias ----------------
template <int MODE>
__global__ __launch_bounds__(256, 2)
void gemm_kernel(const bf16* __restrict__ A, const bf16* __restrict__ Bt,
                 const float* __restrict__ bias, void* __restrict__ Cout) {
    const int K = 1024;
    __shared__ __attribute__((aligned(16))) uint8_t ldsb[32768];
    const int t = threadIdx.x, w = t >> 6, ln = t & 63;
    const int g = ln >> 4, c = ln & 15;
    const int wm = w >> 1, wn = w & 1;
    const int bm = blockIdx.x, bn = blockIdx.y;

    const bf16* Ab = A  + (size_t)bm * 128 * K;
    const bf16* Bb = Bt + (size_t)bn * 128 * K;

    f32x4 zero = {0.f, 0.f, 0.f, 0.f};
    f32x4 acc[4][4];
#pragma unroll
    for (int mi = 0; mi < 4; ++mi)
#pragma unroll
        for (int ni = 0; ni < 4; ++ni) acc[mi][ni] = zero;

    const int srow = ln >> 3;
    const int scol = ((ln & 7) ^ srow) * 8;

    for (int kt = 0; kt < 16; ++kt) {
        const int k0 = kt * 64;
        __syncthreads();
#pragma unroll
        for (int i = 0; i < 4; ++i) {
            const int call = w * 4 + i;
            const int row = call * 8 + srow;
            const bf16* ga = Ab + (size_t)row * K + k0 + scol;
            const bf16* gb = Bb + (size_t)row * K + k0 + scol;
            __builtin_amdgcn_global_load_lds(
                (const __attribute__((address_space(1))) void*)ga,
                (__attribute__((address_space(3))) void*)(ldsb + call * 1024), 16, 0, 0);
            __builtin_amdgcn_global_load_lds(
                (const __attribute__((address_space(1))) void*)gb,
                (__attribute__((address_space(3))) void*)(ldsb + 16384 + call * 1024), 16, 0, 0);
        }
        __syncthreads();
#pragma unroll
        for (int kc = 0; kc < 2; ++kc) {
            bf16x8 af[4], bfr[4];
#pragma unroll
            for (int mi = 0; mi < 4; ++mi) {
                const int lrow = wm * 64 + mi * 16 + c;
                const int cb = (kc * 64 + g * 16) ^ ((lrow & 7) << 4);
                af[mi] = *reinterpret_cast<const bf16x8*>(ldsb + lrow * 128 + cb);
            }
#pragma unroll
            for (int ni = 0; ni < 4; ++ni) {
                const int lrow = wn * 64 + ni * 16 + c;
                const int cb = (kc * 64 + g * 16) ^ ((lrow & 7) << 4);
                bfr[ni] = *reinterpret_cast<const bf16x8*>(ldsb + 16384 + lrow * 128 + cb);
            }
#pragma unroll
            for (int mi = 0; mi < 4; ++mi)
#pragma unroll
                for (int ni = 0; ni < 4; ++ni)
                    acc[mi][ni] = __builtin_amdgcn_mfma_f32_16x16x32_bf16(
                        af[mi], bfr[ni], acc[mi][ni], 0, 0, 0);
        }
    }

#pragma unroll
    for (int mi = 0; mi < 4; ++mi) {
#pragma unroll
        for (int ni = 0; ni < 4; ++ni) {
            const int mrow = bm * 128 + wm * 64 + mi * 16 + g * 4;
            const int ncol = bn * 128 + wn * 64 + ni * 16 + c;
            const float bv_ = bias[ncol];
            if (MODE == 0) {
                const int which = ncol >> 10, hh = (ncol >> 6) & 15, dk = ncol & 63;
                const size_t bh64 = (size_t)((mrow >> 11) * 16 + hh);
                const int sI = mrow & 2047;
                if (which == 2) {
                    bf16x4 p4;
#pragma unroll
                    for (int j = 0; j < 4; ++j) p4[j] = (bf16)(acc[mi][ni][j] + bv_);
                    *reinterpret_cast<bf16x4*>((bf16*)Cout + 2 * REGION +
                                               (bh64 * 64 + dk) * S_ + sI) = p4;
                } else {
                    const float sc = (which == 0) ? QSCALE : 1.0f;
                    bf16* dst = (bf16*)Cout + (size_t)which * REGION +
                                (bh64 * S_ + sI) * 64 + dk;
#pragma unroll
                    for (int j = 0; j < 4; ++j)
                        dst[(size_t)j * 64] = (bf16)((acc[mi][ni][j] + bv_) * sc);
                }
            } else {
#pragma unroll
                for (int j = 0; j < 4; ++j)
                    ((float*)Cout)[(size_t)(mrow + j) * D_ + ncol] = acc[mi][ni][j] + bv_;
            }
        }
    }
}

// ---------------- fused attention v5 ----------------
// v4 structure (64 q/wave, sigma-staged swapped QK^T, in-register P) with the
// T4 counted-vmcnt pipeline: 3-buffer K/V rotation, raw s_barrier, per-wave
// s_waitcnt vmcnt(4) -- tile t+1/t+2 loads stay in flight across barriers.
// Each wave issues exactly 4 global_load_lds per tile; vmcnt(4) ==> own tile-t
// loads landed; barrier ==> all waves' landed. No vmcnt(0) drain in the loop.

__global__ __launch_bounds__(256, 2)
void attn_kernel(const bf16* __restrict__ Q, const bf16* __restrict__ K,
                 const bf16* __restrict__ Vt, bf16* __restrict__ cat) {
    __shared__ __attribute__((aligned(16))) bf16 KsA[3][64 * 64];
    __shared__ __attribute__((aligned(16))) bf16 VsA[3][64 * 64];
    __shared__ float red[4][64];
    const int t = threadIdx.x, w = t >> 6, lane = t & 63;
    const int l31 = lane & 31, h = lane >> 5;

    const int bid = blockIdx.x;
    const int nid = (bid & 7) * 64 + (bid >> 3);    // XCD-chunked, bijective (512%8==0)
    const int bh = nid >> 3, qb = nid & 7;
    const int q0 = qb * 256 + w * 64;               // wave owns q0 .. q0+63

    const bf16* Qg = Q  + ((size_t)bh * S_ + q0) * 64;
    const bf16* Kg = K  + (size_t)bh * S_ * 64;
    const bf16* Vg = Vt + (size_t)bh * 64 * S_;

    // Q B-frags for both sub-tiles: lane holds Q[q=32*qt+l31][dc*16 + h*8 + i]
    bf16x8 qf[2][4];
#pragma unroll
    for (int qt = 0; qt < 2; ++qt)
#pragma unroll
        for (int dc = 0; dc < 4; ++dc)
            qf[qt][dc] = *reinterpret_cast<const bf16x8*>(
                Qg + (size_t)(qt * 32 + l31) * 64 + dc * 16 + h * 8);

    const int sr = lane >> 3, ss = lane & 7;
    const int swz = (ss ^ sr) * 8;

    auto STAGE_KV = [&](int buf, int kv0) {
#pragma unroll
        for (int cc = 0; cc < 2; ++cc) {
            const int row = w * 16 + cc * 8;
            const int rr = row + sr;
            // sigma: swap bits 2<->3 of the LDS row -> score row r holds key sigma(r)
            const int rs = (rr & ~12) | ((rr & 4) << 1) | ((rr & 8) >> 1);
            __builtin_amdgcn_global_load_lds(
                (const __attribute__((address_space(1))) void*)
                    (Kg + (size_t)(kv0 + rs) * 64 + swz),
                (__attribute__((address_space(3))) void*)(&KsA[buf][row * 64]), 16, 0, 0);
            __builtin_amdgcn_global_load_lds(
                (const __attribute__((address_space(1))) void*)
                    (Vg + (size_t)(rr) * S_ + kv0 + swz),
                (__attribute__((address_space(3))) void*)(&VsA[buf][row * 64]), 16, 0, 0);
        }
    };

    f32x16 o[2][2];          // [qt][nb]
    f32x16 lsv[2];           // vector lsum per sub-tile
#pragma unroll
    for (int qt = 0; qt < 2; ++qt) {
#pragma unroll
        for (int j = 0; j < 16; ++j) { o[qt][0][j] = 0.f; o[qt][1][j] = 0.f; lsv[qt][j] = 0.f; }
    }

    STAGE_KV(0, 0);
    STAGE_KV(1, 64);
    int cur = 0;
    for (int it = 0; it < 32; ++it) {
        // own tile-t loads are the oldest 4 outstanding (t+1,t+2 stay in flight)
        if (it < 31) asm volatile("s_waitcnt vmcnt(4)" ::: "memory");
        else         asm volatile("s_waitcnt vmcnt(0)" ::: "memory");
        __builtin_amdgcn_s_barrier();
        __builtin_amdgcn_sched_barrier(0);
        if (it + 2 < 32) STAGE_KV((it + 2) % 3, (it + 2) * 64);
        const bf16* ks = &KsA[cur][0];
        const bf16* vs = &VsA[cur][0];
#pragma unroll
        for (int kb = 0; kb < 2; ++kb) {
            // K-frags read once, used by both q-sub-tiles
            bf16x8 kf[4];
#pragma unroll
            for (int dc = 0; dc < 4; ++dc) {
                const int row = kb * 32 + l31;
                const int slot = (2 * dc + h) ^ (row & 7);
                kf[dc] = *reinterpret_cast<const bf16x8*>(ks + row * 64 + slot * 8);
            }
            f32x16 s0, s1;
#pragma unroll
            for (int j = 0; j < 16; ++j) { s0[j] = 0.f; s1[j] = 0.f; }
            __builtin_amdgcn_s_setprio(1);
#pragma unroll
            for (int dc = 0; dc < 4; ++dc) {
                s0 = __builtin_amdgcn_mfma_f32_32x32x16_bf16(kf[dc], qf[0][dc], s0, 0, 0, 0);
                s1 = __builtin_amdgcn_mfma_f32_32x32x16_bf16(kf[dc], qf[1][dc], s1, 0, 0, 0);
            }
            __builtin_amdgcn_s_setprio(0);
            // p = exp2(s); sigma-staging makes p[0..7] the t2=0 key slice,
            // p[8..15] the t2=1 slice.
            f32x16 p0, p1;
#pragma unroll
            for (int j = 0; j < 16; ++j) p0[j] = __builtin_amdgcn_exp2f(s0[j]);
#pragma unroll
            for (int j = 0; j < 16; ++j) p1[j] = __builtin_amdgcn_exp2f(s1[j]);
            lsv[0] += p0;
            lsv[1] += p1;
            bf16x8 a00, a01, a10, a11;
#pragma unroll
            for (int e = 0; e < 8; ++e) {
                a00[e] = (bf16)p0[e]; a01[e] = (bf16)p0[8 + e];
                a10[e] = (bf16)p1[e]; a11[e] = (bf16)p1[8 + e];
            }
            __builtin_amdgcn_s_setprio(1);
#pragma unroll
            for (int t2 = 0; t2 < 2; ++t2) {
#pragma unroll
                for (int nb = 0; nb < 2; ++nb) {
                    const int row = l31 + 32 * nb;
                    const int slot = (4 * kb + 2 * t2 + h) ^ (row & 7);
                    bf16x8 vf = *reinterpret_cast<const bf16x8*>(vs + row * 64 + slot * 8);
                    o[0][nb] = __builtin_amdgcn_mfma_f32_32x32x16_bf16(
                        t2 ? a01 : a00, vf, o[0][nb], 0, 0, 0);
                    o[1][nb] = __builtin_amdgcn_mfma_f32_32x32x16_bf16(
                        t2 ? a11 : a10, vf, o[1][nb], 0, 0, 0);
                }
            }
            __builtin_amdgcn_s_setprio(0);
        }
        cur = (cur == 2) ? 0 : cur + 1;
    }

    // reduce vector lsum -> scalar per query; combine h-halves; distribute via LDS
#pragma unroll
    for (int qt = 0; qt < 2; ++qt) {
        float s = 0.f;
#pragma unroll
        for (int j = 0; j < 16; ++j) s += lsv[qt][j];
        s += __shfl_xor(s, 32, 64);
        if (h == 0) red[w][qt * 32 + l31] = 1.0f / s;
    }
    const int b = bh >> 4, hh = bh & 15;
#pragma unroll
    for (int qt = 0; qt < 2; ++qt)
#pragma unroll
        for (int j = 0; j < 16; ++j) {
            const int q = qt * 32 + (j & 3) + 8 * (j >> 2) + 4 * h;
            const float rr = red[w][q];
            bf16* dst = cat + ((size_t)b * S_ + q0 + q) * D_ + hh * 64 + l31;
            dst[0]  = (bf16)(o[qt][0][j] * rr);
            dst[32] = (bf16)(o[qt][1][j] * rr);
        }
}

// ---------------- launch ----------------
extern "C" void kernel_launch(void* const* d_in, const int* in_sizes, int n_in,
                              void* d_out, int out_size, void* d_ws, size_t ws_size,
                              hipStream_t stream) {
    const float* x  = (const float*)d_in[0];
    const float* Wq = (const float*)d_in[1];
    const float* bq = (const float*)d_in[2];
    const float* Wk = (const float*)d_in[3];
    const float* bk = (const float*)d_in[4];
    const float* Wv = (const float*)d_in[5];
    const float* bv = (const float*)d_in[6];
    const float* Wo = (const float*)d_in[7];
    const float* bo = (const float*)d_in[8];
    float* out = (float*)d_out;
    char* ws = (char*)d_ws;

    bf16*  xb    = (bf16*)(ws);                          // 16 MB
    bf16*  cat   = (bf16*)(ws + 16777216LL);             // 16 MB
    bf16*  WqkvT = (bf16*)(ws + 33554432LL);             // 6 MB
    bf16*  WoT   = (bf16*)(ws + 39845888LL);             // 2 MB
    float* qkvb  = (float*)(ws + 41943040LL);            // 12 KB
    bf16*  Qb    = (bf16*)(ws + 41955328LL);             // Q | K | Vt regions (3 x 16 MB)
    bf16*  Kb    = Qb + REGION;
    bf16*  Vtb   = Qb + 2 * REGION;

    hipLaunchKernelGGL(cast_x_kernel, dim3(4096), dim3(256), 0, stream, x, xb);
    hipLaunchKernelGGL(prep_wqkv_kernel, dim3(1536), dim3(256), 0, stream,
                       Wq, Wk, Wv, bq, bk, bv, WqkvT, qkvb);
    hipLaunchKernelGGL(prep_wo_kernel, dim3(16, 16), dim3(256), 0, stream, Wo, WoT);
    hipLaunchKernelGGL((gemm_kernel<0>), dim3(64, 24), dim3(256), 0, stream,
                       xb, WqkvT, qkvb, (void*)Qb);
    hipLaunchKernelGGL(attn_kernel, dim3(512), dim3(256), 0, stream, Qb, Kb, Vtb, cat);
    hipLaunchKernelGGL((gemm_kernel<1>), dim3(64, 8), dim3(256), 0, stream,
                       cat, WoT, bo, (void*)out);
}

// Round 6
// 191.168 us; speedup vs baseline: 1.0116x; 1.0116x over previous
//
#include <hip/hip_runtime.h>
#include <hip/hip_bf16.h>
#include <stdint.h>

typedef __bf16 bf16;
typedef __bf16 bf16x8 __attribute__((ext_vector_type(8)));
typedef __bf16 bf16x4 __attribute__((ext_vector_type(4)));
typedef float  f32x4  __attribute__((ext_vector_type(4)));
typedef float  f32x16 __attribute__((ext_vector_type(16)));

#define H_   16
#define D_   1024
#define B_   4
#define S_   2048
#define M_   (B_*S_)      // 8192 rows
#define REGION 8388608LL  // elems per Q/K/V region

// Q is pre-scaled by 1/sqrt(dk) * log2(e) so attention uses raw exp2.
#define QSCALE 0.18033688011112042f

// ---------------- prep kernels ----------------

__global__ void cast_x_kernel(const float* __restrict__ x, bf16* __restrict__ xb) {
    const int i = blockIdx.x * 256 + threadIdx.x;
    const float4* src = reinterpret_cast<const float4*>(x) + (size_t)i * 2;
    float4 a = src[0], b = src[1];
    bf16x8 o;
    o[0]=(bf16)a.x; o[1]=(bf16)a.y; o[2]=(bf16)a.z; o[3]=(bf16)a.w;
    o[4]=(bf16)b.x; o[5]=(bf16)b.y; o[6]=(bf16)b.z; o[7]=(bf16)b.w;
    *reinterpret_cast<bf16x8*>(xb + (size_t)i * 8) = o;
}

__global__ void prep_wqkv_kernel(const float* __restrict__ Wq, const float* __restrict__ Wk,
                                 const float* __restrict__ Wv, const float* __restrict__ bq,
                                 const float* __restrict__ bk, const float* __restrict__ bv,
                                 bf16* __restrict__ WqkvT, float* __restrict__ qkvb) {
    const int t = blockIdx.x * 256 + threadIdx.x;
    const int n = t >> 7, d0 = (t & 127) << 3;
    const int which = n >> 10, hh = (n >> 6) & 15, dk = n & 63;
    const float* W = (which == 0) ? Wq : (which == 1) ? Wk : Wv;
    const float* src = W + (size_t)hh * 65536 + (size_t)d0 * 64 + dk;
    bf16x8 o;
#pragma unroll
    for (int i = 0; i < 8; ++i) o[i] = (bf16)src[(size_t)i * 64];
    *reinterpret_cast<bf16x8*>(WqkvT + (size_t)n * D_ + d0) = o;
    if (d0 == 0) {
        const float* bb = (which == 0) ? bq : (which == 1) ? bk : bv;
        qkvb[n] = bb[n & 1023];
    }
}

__global__ void prep_wo_kernel(const float* __restrict__ Wo, bf16* __restrict__ WoT) {
    __shared__ float tile[64][65];
    const int k0 = blockIdx.x * 64, n0 = blockIdx.y * 64;
    const int t = threadIdx.x;
#pragma unroll
    for (int i = 0; i < 16; ++i) {
        int idx = t + i * 256, r = idx >> 6, c = idx & 63;
        tile[r][c] = Wo[(size_t)(k0 + r) * D_ + n0 + c];
    }
    __syncthreads();
#pragma unroll
    for (int i = 0; i < 16; ++i) {
        int idx = t + i * 256, n = idx >> 6, k = idx & 63;
        WoT[(size_t)(n0 + n) * D_ + k0 + k] = (bf16)tile[k][n];
    }
}

// ---------------- GEMM: C[M][N] = A[M][1024] * Bt[N][1024]^T + bias ----------------
// launch_bounds (256,3): VGPR cap 170 -> 3 blocks/CU (was self-capped at 2).
template <int MODE>
__global__ __launch_bounds__(256, 3)
void gemm_kernel(const bf16* __restrict__ A, const bf16* __restrict__ Bt,
                 const float* __restrict__ bias, void* __restrict__ Cout) {
    const int K = 1024;
    __shared__ __attribute__((aligned(16))) uint8_t ldsb[32768];
    const int t = threadIdx.x, w = t >> 6, ln = t & 63;
    const int g = ln >> 4, c = ln & 15;
    const int wm = w >> 1, wn = w & 1;
    const int bm = blockIdx.x, bn = blockIdx.y;

    const bf16* Ab = A  + (size_t)bm * 128 * K;
    const bf16* Bb = Bt + (size_t)bn * 128 * K;

    f32x4 zero = {0.f, 0.f, 0.f, 0.f};
    f32x4 acc[4][4];
#pragma unroll
    for (int mi = 0; mi < 4; ++mi)
#pragma unroll
        for (int ni = 0; ni < 4; ++ni) acc[mi][ni] = zero;

    const int srow = ln >> 3;
    const int scol = ((ln & 7) ^ srow) * 8;

    for (int kt = 0; kt < 16; ++kt) {
        const int k0 = kt * 64;
        __syncthreads();
#pragma unroll
        for (int i = 0; i < 4; ++i) {
            const int call = w * 4 + i;
            const int row = call * 8 + srow;
            const bf16* ga = Ab + (size_t)row * K + k0 + scol;
            const bf16* gb = Bb + (size_t)row * K + k0 + scol;
            __builtin_amdgcn_global_load_lds(
                (const __attribute__((address_space(1))) void*)ga,
                (__attribute__((address_space(3))) void*)(ldsb + call * 1024), 16, 0, 0);
            __builtin_amdgcn_global_load_lds(
                (const __attribute__((address_space(1))) void*)gb,
                (__attribute__((address_space(3))) void*)(ldsb + 16384 + call * 1024), 16, 0, 0);
        }
        __syncthreads();
#pragma unroll
        for (int kc = 0; kc < 2; ++kc) {
            bf16x8 af[4], bfr[4];
#pragma unroll
            for (int mi = 0; mi < 4; ++mi) {
                const int lrow = wm * 64 + mi * 16 + c;
                const int cb = (kc * 64 + g * 16) ^ ((lrow & 7) << 4);
                af[mi] = *reinterpret_cast<const bf16x8*>(ldsb + lrow * 128 + cb);
            }
#pragma unroll
            for (int ni = 0; ni < 4; ++ni) {
                const int lrow = wn * 64 + ni * 16 + c;
                const int cb = (kc * 64 + g * 16) ^ ((lrow & 7) << 4);
                bfr[ni] = *reinterpret_cast<const bf16x8*>(ldsb + 16384 + lrow * 128 + cb);
            }
#pragma unroll
            for (int mi = 0; mi < 4; ++mi)
#pragma unroll
                for (int ni = 0; ni < 4; ++ni)
                    acc[mi][ni] = __builtin_amdgcn_mfma_f32_16x16x32_bf16(
                        af[mi], bfr[ni], acc[mi][ni], 0, 0, 0);
        }
    }

#pragma unroll
    for (int mi = 0; mi < 4; ++mi) {
#pragma unroll
        for (int ni = 0; ni < 4; ++ni) {
            const int mrow = bm * 128 + wm * 64 + mi * 16 + g * 4;
            const int ncol = bn * 128 + wn * 64 + ni * 16 + c;
            const float bv_ = bias[ncol];
            if (MODE == 0) {
                const int which = ncol >> 10, hh = (ncol >> 6) & 15, dk = ncol & 63;
                const size_t bh64 = (size_t)((mrow >> 11) * 16 + hh);
                const int sI = mrow & 2047;
                if (which == 2) {
                    bf16x4 p4;
#pragma unroll
                    for (int j = 0; j < 4; ++j) p4[j] = (bf16)(acc[mi][ni][j] + bv_);
                    *reinterpret_cast<bf16x4*>((bf16*)Cout + 2 * REGION +
                                               (bh64 * 64 + dk) * S_ + sI) = p4;
                } else {
                    const float sc = (which == 0) ? QSCALE : 1.0f;
                    bf16* dst = (bf16*)Cout + (size_t)which * REGION +
                                (bh64 * S_ + sI) * 64 + dk;
#pragma unroll
                    for (int j = 0; j < 4; ++j)
                        dst[(size_t)j * 64] = (bf16)((acc[mi][ni][j] + bv_) * sc);
                }
            } else {
#pragma unroll
                for (int j = 0; j < 4; ++j)
                    ((float*)Cout)[(size_t)(mrow + j) * D_ + ncol] = acc[mi][ni][j] + bv_;
            }
        }
    }
}

// ---------------- fused attention v6 ----------------
// v4 skeleton (2-buffer, __syncthreads). New: (a) persistent fz zero-vector as
// the C-input of each QK chain's first MFMA (kills 128 v_mov/wave/iter of
// accumulator re-zeroing); (b) wave-pair kb stagger (waves 0,1: kb {0,1};
// waves 2,3: kb {1,0}) to anti-phase MFMA vs exp/cvt across wave pairs.

__global__ __launch_bounds__(256, 2)
void attn_kernel(const bf16* __restrict__ Q, const bf16* __restrict__ K,
                 const bf16* __restrict__ Vt, bf16* __restrict__ cat) {
    __shared__ __attribute__((aligned(16))) bf16 KsA[2][64 * 64];
    __shared__ __attribute__((aligned(16))) bf16 VsA[2][64 * 64];
    __shared__ float red[4][64];
    const int t = threadIdx.x, w = t >> 6, lane = t & 63;
    const int l31 = lane & 31, h = lane >> 5;
    const int ko = (w >> 1) & 1;                    // kb order stagger per wave-pair

    const int bid = blockIdx.x;
    const int nid = (bid & 7) * 64 + (bid >> 3);    // XCD-chunked, bijective (512%8==0)
    const int bh = nid >> 3, qb = nid & 7;
    const int q0 = qb * 256 + w * 64;               // wave owns q0 .. q0+63

    const bf16* Qg = Q  + ((size_t)bh * S_ + q0) * 64;
    const bf16* Kg = K  + (size_t)bh * S_ * 64;
    const bf16* Vg = Vt + (size_t)bh * 64 * S_;

    // Q B-frags for both sub-tiles: lane holds Q[q=32*qt+l31][dc*16 + h*8 + i]
    bf16x8 qf[2][4];
#pragma unroll
    for (int qt = 0; qt < 2; ++qt)
#pragma unroll
        for (int dc = 0; dc < 4; ++dc)
            qf[qt][dc] = *reinterpret_cast<const bf16x8*>(
                Qg + (size_t)(qt * 32 + l31) * 64 + dc * 16 + h * 8);

    const int sr = lane >> 3, ss = lane & 7;
    const int swz = (ss ^ sr) * 8;

    auto STAGE_KV = [&](int buf, int kv0) {
#pragma unroll
        for (int cc = 0; cc < 2; ++cc) {
            const int row = w * 16 + cc * 8;
            const int rr = row + sr;
            // sigma: swap bits 2<->3 of the LDS row -> score row r holds key sigma(r)
            const int rs = (rr & ~12) | ((rr & 4) << 1) | ((rr & 8) >> 1);
            __builtin_amdgcn_global_load_lds(
                (const __attribute__((address_space(1))) void*)
                    (Kg + (size_t)(kv0 + rs) * 64 + swz),
                (__attribute__((address_space(3))) void*)(&KsA[buf][row * 64]), 16, 0, 0);
            __builtin_amdgcn_global_load_lds(
                (const __attribute__((address_space(1))) void*)
                    (Vg + (size_t)(rr) * S_ + kv0 + swz),
                (__attribute__((address_space(3))) void*)(&VsA[buf][row * 64]), 16, 0, 0);
        }
    };

    f32x16 fz;               // persistent zero C-input (never clobbered -> LICM hoists)
#pragma unroll
    for (int j = 0; j < 16; ++j) fz[j] = 0.f;

    f32x16 o[2][2];          // [qt][nb]
    f32x16 lsv[2];           // vector lsum per sub-tile
#pragma unroll
    for (int qt = 0; qt < 2; ++qt) {
#pragma unroll
        for (int j = 0; j < 16; ++j) { o[qt][0][j] = 0.f; o[qt][1][j] = 0.f; lsv[qt][j] = 0.f; }
    }

    STAGE_KV(0, 0);
    for (int it = 0; it < 32; ++it) {
        __syncthreads();
        if (it + 1 < 32) STAGE_KV((it + 1) & 1, (it + 1) * 64);
        const bf16* ks = KsA[it & 1];
        const bf16* vs = VsA[it & 1];
#pragma unroll
        for (int kb2 = 0; kb2 < 2; ++kb2) {
            const int kb = kb2 ^ ko;
            // K-frags read once, used by both q-sub-tiles
            bf16x8 kf[4];
#pragma unroll
            for (int dc = 0; dc < 4; ++dc) {
                const int row = kb * 32 + l31;
                const int slot = (2 * dc + h) ^ (row & 7);
                kf[dc] = *reinterpret_cast<const bf16x8*>(ks + row * 64 + slot * 8);
            }
            __builtin_amdgcn_s_setprio(1);
            f32x16 s0 = __builtin_amdgcn_mfma_f32_32x32x16_bf16(kf[0], qf[0][0], fz, 0, 0, 0);
            f32x16 s1 = __builtin_amdgcn_mfma_f32_32x32x16_bf16(kf[0], qf[1][0], fz, 0, 0, 0);
#pragma unroll
            for (int dc = 1; dc < 4; ++dc) {
                s0 = __builtin_amdgcn_mfma_f32_32x32x16_bf16(kf[dc], qf[0][dc], s0, 0, 0, 0);
                s1 = __builtin_amdgcn_mfma_f32_32x32x16_bf16(kf[dc], qf[1][dc], s1, 0, 0, 0);
            }
            __builtin_amdgcn_s_setprio(0);
            // p = exp2(s); sigma-staging makes p[0..7] the t2=0 key slice,
            // p[8..15] the t2=1 slice.
            f32x16 p0, p1;
#pragma unroll
            for (int j = 0; j < 16; ++j) p0[j] = __builtin_amdgcn_exp2f(s0[j]);
#pragma unroll
            for (int j = 0; j < 16; ++j) p1[j] = __builtin_amdgcn_exp2f(s1[j]);
            lsv[0] += p0;
            lsv[1] += p1;
            bf16x8 a00, a01, a10, a11;
#pragma unroll
            for (int e = 0; e < 8; ++e) {
                a00[e] = (bf16)p0[e]; a01[e] = (bf16)p0[8 + e];
                a10[e] = (bf16)p1[e]; a11[e] = (bf16)p1[8 + e];
            }
            __builtin_amdgcn_s_setprio(1);
#pragma unroll
            for (int t2 = 0; t2 < 2; ++t2) {
#pragma unroll
                for (int nb = 0; nb < 2; ++nb) {
                    const int row = l31 + 32 * nb;
                    const int slot = (4 * kb + 2 * t2 + h) ^ (row & 7);
                    bf16x8 vf = *reinterpret_cast<const bf16x8*>(vs + row * 64 + slot * 8);
                    o[0][nb] = __builtin_amdgcn_mfma_f32_32x32x16_bf16(
                        t2 ? a01 : a00, vf, o[0][nb], 0, 0, 0);
                    o[1][nb] = __builtin_amdgcn_mfma_f32_32x32x16_bf16(
                        t2 ? a11 : a10, vf, o[1][nb], 0, 0, 0);
                }
            }
            __builtin_amdgcn_s_setprio(0);
        }
    }

    // reduce vector lsum -> scalar per query; combine h-halves; distribute via LDS
#pragma unroll
    for (int qt = 0; qt < 2; ++qt) {
        float s = 0.f;
#pragma unroll
        for (int j = 0; j < 16; ++j) s += lsv[qt][j];
        s += __shfl_xor(s, 32, 64);
        if (h == 0) red[w][qt * 32 + l31] = 1.0f / s;
    }
    const int b = bh >> 4, hh = bh & 15;
#pragma unroll
    for (int qt = 0; qt < 2; ++qt)
#pragma unroll
        for (int j = 0; j < 16; ++j) {
            const int q = qt * 32 + (j & 3) + 8 * (j >> 2) + 4 * h;
            const float rr = red[w][q];
            bf16* dst = cat + ((size_t)b * S_ + q0 + q) * D_ + hh * 64 + l31;
            dst[0]  = (bf16)(o[qt][0][j] * rr);
            dst[32] = (bf16)(o[qt][1][j] * rr);
        }
}

// ---------------- launch ----------------
extern "C" void kernel_launch(void* const* d_in, const int* in_sizes, int n_in,
                              void* d_out, int out_size, void* d_ws, size_t ws_size,
                              hipStream_t stream) {
    const float* x  = (const float*)d_in[0];
    const float* Wq = (const float*)d_in[1];
    const float* bq = (const float*)d_in[2];
    const float* Wk = (const float*)d_in[3];
    const float* bk = (const float*)d_in[4];
    const float* Wv = (const float*)d_in[5];
    const float* bv = (const float*)d_in[6];
    const float* Wo = (const float*)d_in[7];
    const float* bo = (const float*)d_in[8];
    float* out = (float*)d_out;
    char* ws = (char*)d_ws;

    bf16*  xb    = (bf16*)(ws);                          // 16 MB
    bf16*  cat   = (bf16*)(ws + 16777216LL);             // 16 MB
    bf16*  WqkvT = (bf16*)(ws + 33554432LL);             // 6 MB
    bf16*  WoT   = (bf16*)(ws + 39845888LL);             // 2 MB
    float* qkvb  = (float*)(ws + 41943040LL);            // 12 KB
    bf16*  Qb    = (bf16*)(ws + 41955328LL);             // Q | K | Vt regions (3 x 16 MB)
    bf16*  Kb    = Qb + REGION;
    bf16*  Vtb   = Qb + 2 * REGION;

    hipLaunchKernelGGL(cast_x_kernel, dim3(4096), dim3(256), 0, stream, x, xb);
    hipLaunchKernelGGL(prep_wqkv_kernel, dim3(1536), dim3(256), 0, stream,
                       Wq, Wk, Wv, bq, bk, bv, WqkvT, qkvb);
    hipLaunchKernelGGL(prep_wo_kernel, dim3(16, 16), dim3(256), 0, stream, Wo, WoT);
    hipLaunchKernelGGL((gemm_kernel<0>), dim3(64, 24), dim3(256), 0, stream,
                       xb, WqkvT, qkvb, (void*)Qb);
    hipLaunchKernelGGL(attn_kernel, dim3(512), dim3(256), 0, stream, Qb, Kb, Vtb, cat);
    hipLaunchKernelGGL((gemm_kernel<1>), dim3(64, 8), dim3(256), 0, stream,
                       cat, WoT, bo, (void*)out);
}